// Round 4
// baseline (711.152 us; speedup 1.0000x reference)
//
#include <hip/hip_runtime.h>
#include <cstdint>
#include <cstddef>

// ---------- types ----------
typedef __attribute__((ext_vector_type(8))) __bf16 bf16x8;   // MFMA A/B frag (4 VGPRs)
typedef __attribute__((ext_vector_type(4))) float f32x4;     // MFMA C/D frag

typedef const __attribute__((address_space(1))) unsigned int* gas1_t;
typedef __attribute__((address_space(3))) unsigned int* las3_t;

__device__ __forceinline__ unsigned short f2bf(float f) {    // RNE float->bf16
  unsigned int u = __float_as_uint(f);
  u += 0x7FFFu + ((u >> 16) & 1u);
  return (unsigned short)(u >> 16);
}
__device__ __forceinline__ float bf2f(unsigned short h) {
  return __uint_as_float(((unsigned int)h) << 16);
}

// ---------- runtime dtype detection ----------
__device__ __forceinline__ int detect_f32(const unsigned short* det) {
  int cnt = 0;
#pragma unroll
  for (int i = 0; i < 32; ++i) {
    const unsigned int e = (det[2 * i] >> 7) & 0xFF;
    cnt += (e >= 115 && e <= 135) ? 1 : 0;
  }
  return cnt < 16;   // 1 => buffers are fp32, 0 => bf16
}

// dual-dtype scalar load/store (offsets in ELEMENTS)
__device__ __forceinline__ float loadf(const void* b, size_t i, int f32) {
  return f32 ? ((const float*)b)[i] : bf2f(((const unsigned short*)b)[i]);
}
__device__ __forceinline__ void storef(void* b, size_t i, float v, int f32) {
  if (f32) ((float*)b)[i] = v;
  else     ((unsigned short*)b)[i] = f2bf(v);
}
// dual-dtype 8-element fragment load -> bf16x8 (offset in ELEMENTS, 8-aligned)
__device__ __forceinline__ bf16x8 load8(const void* base, size_t elem, int f32) {
  if (f32) {
    const float* p = (const float*)base + elem;
    const float4 a = *(const float4*)p;
    const float4 b = *(const float4*)(p + 4);
    bf16x8 r;
    unsigned short* q = (unsigned short*)&r;
    q[0] = f2bf(a.x); q[1] = f2bf(a.y); q[2] = f2bf(a.z); q[3] = f2bf(a.w);
    q[4] = f2bf(b.x); q[5] = f2bf(b.y); q[6] = f2bf(b.z); q[7] = f2bf(b.w);
    return r;
  }
  return *(const bf16x8*)((const unsigned short*)base + elem);
}

// ---------------------------------------------------------------------------
// convert_kernel: fp32 (or bf16) inputs -> bf16 workspace, one pass, PLUS the
// past-slab copy (new_{k,v}[0:256] = past_{k,v}[256:512]) folded in as extra
// blocks (blockIdx >= 4096) so it overlaps the convert BW.
//   x   (4096x2048)           -> xb
//   Wq,Wk,Wv (each 2048x2048) -> wqkv (row-concat [6144][2048])
//   Wo  (2048x2048)           -> wob
// ---------------------------------------------------------------------------
__global__ __launch_bounds__(256) void convert_kernel(
    const void* __restrict__ x,  const void* __restrict__ wq,
    const void* __restrict__ wk, const void* __restrict__ wv,
    const void* __restrict__ wo,
    const void* __restrict__ past_k, const void* __restrict__ past_v,
    void* __restrict__ dout,
    unsigned short* __restrict__ xb, unsigned short* __restrict__ wqkv,
    unsigned short* __restrict__ wob, const unsigned short* __restrict__ det)
{
  const int f32 = detect_f32(det);
  const int tid = threadIdx.x;
  if (blockIdx.x >= 4096) {   // ---- fused past-slab copy ----
    const int es  = f32 ? 4 : 2;
    const int bh  = blockIdx.x - 4096;
    const size_t srcOff  = ((size_t)bh * 512 + 256) * 64 * es;
    const size_t dstKOff = ((size_t)8388608  + (size_t)bh * 512 * 64) * es;
    const size_t dstVOff = ((size_t)25165824 + (size_t)bh * 512 * 64) * es;
    const uint4* sK = (const uint4*)((const char*)past_k + srcOff);
    const uint4* sV = (const uint4*)((const char*)past_v + srcOff);
    uint4* dK = (uint4*)((char*)dout + dstKOff);
    uint4* dV = (uint4*)((char*)dout + dstVOff);
    const int n4 = 16384 * es / 16;
    for (int c = tid; c < n4; c += 256) { dK[c] = sK[c]; dV[c] = sV[c]; }
    return;
  }
  int c = blockIdx.x * 256 + tid;
#pragma unroll
  for (int it = 0; it < 3; ++it, c += 1048576) {
    bf16x8 v; unsigned short* dp;
    if (c < 1048576) {
      v = load8(x, (size_t)c << 3, f32);                     dp = xb   + ((size_t)c << 3);
    } else if (c < 1572864) {
      v = load8(wq, (size_t)(c - 1048576) << 3, f32);        dp = wqkv + ((size_t)(c - 1048576) << 3);
    } else if (c < 2097152) {
      v = load8(wk, (size_t)(c - 1572864) << 3, f32);        dp = wqkv + 4194304 + ((size_t)(c - 1572864) << 3);
    } else if (c < 2621440) {
      v = load8(wv, (size_t)(c - 2097152) << 3, f32);        dp = wqkv + 8388608 + ((size_t)(c - 2097152) << 3);
    } else {
      v = load8(wo, (size_t)(c - 2621440) << 3, f32);        dp = wob  + ((size_t)(c - 2621440) << 3);
    }
    *(bf16x8*)dp = v;
  }
}

// ---------------------------------------------------------------------------
// gemm_bf16_kernel: C[m,n] = sum_k A[m,k]*W[n,k], A/W bf16, K=2048 fixed.
// 128x128 tile, BK=32, 256 thr = 4 waves, wave = 64x64 via 4x4 of 16x16x32.
// 2-phase double-buffered pipeline (T3-minimum): stage K-tile t+1 via
// global_load_lds width 16 BEFORE computing tile t; ONE __syncthreads per
// K-step (its vmcnt(0)+lgkmcnt(0) drain makes the dbuf race-free: the buffer
// being overwritten was last read before the previous barrier).
// Bank swizzle for 64B rows (4 x 16B chunks): chunk ^= (row>>1)&3, applied on
// the global SOURCE (staging) and the ds_read address (rule #21) -> 8 rows
// hit all 8 bank-slots -> 2-way (free). __launch_bounds__(256,3) caps regs
// for 3 blocks/CU.
// route 0: C -> c0 at m*2048+n, detected dtype.
// route 1: fused QKV epilogue (Q->c0 bf16 scatter; K/V->dko detected dtype).
// ---------------------------------------------------------------------------
__global__ __launch_bounds__(256, 3) void gemm_bf16_kernel(
    const unsigned short* __restrict__ A,   // [M][2048] bf16
    const unsigned short* __restrict__ W,   // [N][2048] bf16
    void* __restrict__ c0,
    void* __restrict__ dko,
    const unsigned short* __restrict__ det,
    int route)
{
  __shared__ __align__(16) unsigned short As[2][128 * 32];  // 2 x 8 KiB
  __shared__ __align__(16) unsigned short Bs[2][128 * 32];  // 2 x 8 KiB
  const int f32 = detect_f32(det);

  const int tid  = threadIdx.x;
  const int lane = tid & 63;
  const int wave = tid >> 6;
  const int quad = lane >> 4;
  const int l16  = lane & 15;

  // XCD-chunked swizzle (bijective since gridDim.x % 8 == 0)
  const int qq  = gridDim.x >> 3;
  const int swz = (blockIdx.x & 7) * qq + (blockIdx.x >> 3);
  const int mBase = (swz & 31) * 128;
  const int nBase = (swz >> 5) * 128;

  const int wm = (wave >> 1) * 64;
  const int wn = (wave & 1) * 64;

  // staging role: slot0 = row tid>>2 chunk tid&3, slot1 = +64 rows.
  // LDS dest linear = tid*16 B (wave-uniform base + lane*16, as required).
  // Source chunk pre-swizzled by key (row>>1)&3 = (tid>>3)&3.
  const int schk = (tid & 3) ^ ((tid >> 3) & 3);
  const unsigned short* Ap = A + (size_t)(mBase + (tid >> 2)) * 2048 + (schk << 3);
  const unsigned short* Wp = W + (size_t)(nBase + (tid >> 2)) * 2048 + (schk << 3);

  // read-side swizzled byte offset within a 64B row (key depends on l16 only,
  // since wm/wn + i*16 are multiples of 16)
  const int rdOff = ((quad ^ ((l16 >> 1) & 3)) << 4);

  f32x4 acc[4][4];
#pragma unroll
  for (int i = 0; i < 4; ++i)
#pragma unroll
    for (int j = 0; j < 4; ++j) acc[i][j] = f32x4{0.f, 0.f, 0.f, 0.f};

#define STAGE(bufi, kb) do {                                                   \
    __builtin_amdgcn_global_load_lds((gas1_t)(Ap + (kb)),                      \
        (las3_t)&As[bufi][tid * 8], 16, 0, 0);                                 \
    __builtin_amdgcn_global_load_lds((gas1_t)(Ap + (kb) + 131072),             \
        (las3_t)&As[bufi][2048 + tid * 8], 16, 0, 0);                          \
    __builtin_amdgcn_global_load_lds((gas1_t)(Wp + (kb)),                      \
        (las3_t)&Bs[bufi][tid * 8], 16, 0, 0);                                 \
    __builtin_amdgcn_global_load_lds((gas1_t)(Wp + (kb) + 131072),             \
        (las3_t)&Bs[bufi][2048 + tid * 8], 16, 0, 0);                          \
  } while (0)

#define COMPUTE(bufi) do {                                                     \
    bf16x8 af[4], bfr[4];                                                      \
    const char* baseA = (const char*)&As[bufi][0];                             \
    const char* baseB = (const char*)&Bs[bufi][0];                             \
    _Pragma("unroll")                                                          \
    for (int i = 0; i < 4; ++i) {                                              \
      af[i]  = *(const bf16x8*)(baseA + (wm + i * 16 + l16) * 64 + rdOff);     \
      bfr[i] = *(const bf16x8*)(baseB + (wn + i * 16 + l16) * 64 + rdOff);     \
    }                                                                          \
    _Pragma("unroll")                                                          \
    for (int i = 0; i < 4; ++i)                                                \
      _Pragma("unroll")                                                        \
      for (int j = 0; j < 4; ++j)                                              \
        acc[i][j] = __builtin_amdgcn_mfma_f32_16x16x32_bf16(af[i], bfr[j],     \
                                                            acc[i][j], 0, 0, 0); \
  } while (0)

  STAGE(0, 0);
  __syncthreads();
  int cur = 0;
#pragma unroll 2
  for (int t = 1; t < 64; ++t) {
    STAGE(cur ^ 1, t * 32);    // prefetch next tile (flies under the MFMAs)
    COMPUTE(cur);
    __syncthreads();           // drains vmcnt+lgkmcnt, then barrier
    cur ^= 1;
  }
  COMPUTE(cur);

#undef STAGE
#undef COMPUTE

  // epilogue: C/D layout col=lane&15, row=quad*4+reg
#pragma unroll
  for (int i = 0; i < 4; ++i) {
#pragma unroll
    for (int j = 0; j < 4; ++j) {
#pragma unroll
      for (int r = 0; r < 4; ++r) {
        const int m = mBase + wm + i * 16 + quad * 4 + r;
        const int n = nBase + wn + j * 16 + l16;
        if (route == 0) {
          storef(c0, (size_t)m * 2048 + n, acc[i][j][r], f32);
        } else {
          const int b = m >> 8, t = m & 255;
          const int seg = n >> 11;         // uniform per block (2048 % 128 == 0)
          const int nn = n & 2047;
          const int hh = nn >> 6, d = nn & 63;
          if (seg == 0) {
            ((unsigned short*)c0)[(((size_t)(b * 32 + hh)) * 256 + t) * 64 + d] =
                f2bf(acc[i][j][r]);
          } else {
            const size_t coff = (seg == 1) ? (size_t)8388608 : (size_t)25165824;
            storef(dko, coff + (((size_t)(b * 32 + hh)) * 512 + 256 + t) * 64 + d,
                   acc[i][j][r], f32);
          }
        }
      }
    }
  }
}

// ---------------------------------------------------------------------------
// LEGACY GEMM (round-1) -- fallback when workspace < 64 MiB.
// ---------------------------------------------------------------------------
__global__ __launch_bounds__(256) void gemm_bt_kernel(
    const void* __restrict__ A, const void* __restrict__ W, void* __restrict__ C,
    const unsigned short* __restrict__ det,
    int amode, int wmode, int cmode, size_t coff,
    int N, int K, int mode, int S, int t0)
{
  __shared__ __align__(16) unsigned short As[128 * 32];
  __shared__ __align__(16) unsigned short Bs[128 * 32];
  const int f32  = detect_f32(det);
  const int af32 = amode & f32, wf32 = wmode & f32, cf32 = cmode & f32;

  const int tid  = threadIdx.x;
  const int lane = tid & 63;
  const int wave = tid >> 6;
  const int quad = lane >> 4;
  const int l16  = lane & 15;
  const int mBase = blockIdx.x * 128;
  const int nBase = blockIdx.y * 128;
  const int wm = (wave >> 1) * 64;
  const int wn = (wave & 1) * 64;

  const int row0 = tid >> 2,          kc0 = (tid & 3) << 3;
  const int row1 = (256 + tid) >> 2,  kc1 = ((256 + tid) & 3) << 3;

  f32x4 acc[4][4];
#pragma unroll
  for (int i = 0; i < 4; ++i)
#pragma unroll
    for (int j = 0; j < 4; ++j) acc[i][j] = f32x4{0.f, 0.f, 0.f, 0.f};

  for (int kb = 0; kb < K; kb += 32) {
    const bf16x8 a0 = load8(A, (size_t)(mBase + row0) * K + kb + kc0, af32);
    const bf16x8 a1 = load8(A, (size_t)(mBase + row1) * K + kb + kc1, af32);
    const bf16x8 b0 = load8(W, (size_t)(nBase + row0) * K + kb + kc0, wf32);
    const bf16x8 b1 = load8(W, (size_t)(nBase + row1) * K + kb + kc1, wf32);
    __syncthreads();
    *(bf16x8*)&As[(size_t)tid * 8]         = a0;
    *(bf16x8*)&As[(size_t)(256 + tid) * 8] = a1;
    *(bf16x8*)&Bs[(size_t)tid * 8]         = b0;
    *(bf16x8*)&Bs[(size_t)(256 + tid) * 8] = b1;
    __syncthreads();

    bf16x8 af[4], bfr[4];
#pragma unroll
    for (int i = 0; i < 4; ++i)
      af[i]  = *(const bf16x8*)&As[(wm + i * 16 + l16) * 32 + quad * 8];
#pragma unroll
    for (int j = 0; j < 4; ++j)
      bfr[j] = *(const bf16x8*)&Bs[(wn + j * 16 + l16) * 32 + quad * 8];
#pragma unroll
    for (int i = 0; i < 4; ++i)
#pragma unroll
      for (int j = 0; j < 4; ++j)
        acc[i][j] = __builtin_amdgcn_mfma_f32_16x16x32_bf16(af[i], bfr[j], acc[i][j], 0, 0, 0);
  }

#pragma unroll
  for (int i = 0; i < 4; ++i) {
#pragma unroll
    for (int j = 0; j < 4; ++j) {
#pragma unroll
      for (int r = 0; r < 4; ++r) {
        const int m = mBase + wm + i * 16 + quad * 4 + r;
        const int n = nBase + wn + j * 16 + l16;
        size_t idx;
        if (mode == 0) {
          idx = (size_t)m * N + n;
        } else {
          const int b = m >> 8, t = m & 255;
          const int hh = n >> 6, d = n & 63;
          idx = (((size_t)(b * 32 + hh)) * S + (t0 + t)) * 64 + d;
        }
        storef(C, coff + idx, acc[i][j][r], cf32);
      }
    }
  }
}

// ---------------------------------------------------------------------------
// copy past slabs into outputs (legacy path only; fast path fuses into convert)
// ---------------------------------------------------------------------------
__global__ __launch_bounds__(256) void copy_kernel(
    const void* __restrict__ past_k, const void* __restrict__ past_v,
    void* __restrict__ dout, const unsigned short* __restrict__ det)
{
  const int f32 = detect_f32(det);
  const int es  = f32 ? 4 : 2;
  const int bh  = blockIdx.x;
  const int tid = threadIdx.x;
  const size_t srcOff  = ((size_t)bh * 512 + 256) * 64 * es;
  const size_t dstKOff = ((size_t)8388608  + (size_t)bh * 512 * 64) * es;
  const size_t dstVOff = ((size_t)25165824 + (size_t)bh * 512 * 64) * es;
  const uint4* sK = (const uint4*)((const char*)past_k + srcOff);
  const uint4* sV = (const uint4*)((const char*)past_v + srcOff);
  uint4* dK = (uint4*)((char*)dout + dstKOff);
  uint4* dV = (uint4*)((char*)dout + dstVOff);
  const int n4 = 16384 * es / 16;
  for (int c = tid; c < n4; c += 256) { dK[c] = sK[c]; dV[c] = sV[c]; }
}

// ---------------------------------------------------------------------------
// RoPE: which=0 -> q_ws in-place (bf16 ws); which=1 -> new_k[256:] (in d_out,
// detected dtype) -> krot_ws (bf16). Fast intrinsics: angle err ~5e-5 rad,
// far below bf16 resolution.
// ---------------------------------------------------------------------------
__global__ __launch_bounds__(256) void rope_kernel(
    const int* __restrict__ pos_p,
    unsigned short* __restrict__ qbuf,
    const void* __restrict__ dout,
    unsigned short* __restrict__ krot,
    const unsigned short* __restrict__ det)
{
  const int f32 = detect_f32(det);
  const int gid = blockIdx.x * 256 + threadIdx.x;
  const int which = gid >> 22;
  const int pi = gid & ((1 << 22) - 1);
  const int i  = pi & 31;
  const int t  = (pi >> 5) & 255;
  const int bh = pi >> 13;
  const float pos  = (float)(*pos_p + t);
  const float freq = __expf(-(float)i * 0.2878231366242557f);
  float sn, cs;
  __sincosf(pos * freq, &sn, &cs);
  if (which == 0) {
    unsigned short* p = qbuf + (((size_t)bh * 256 + t) * 64 + 2 * i);
    const float a = bf2f(p[0]), b2 = bf2f(p[1]);
    p[0] = f2bf(a * cs - b2 * sn);
    p[1] = f2bf(a * sn + b2 * cs);
  } else {
    const size_t src = 8388608 + (((size_t)bh * 512 + 256 + t) * 64 + 2 * i);
    unsigned short* dp = krot + (((size_t)bh * 256 + t) * 64 + 2 * i);
    const float a = loadf(dout, src, f32), b2 = loadf(dout, src + 1, f32);
    dp[0] = f2bf(a * cs - b2 * sn);
    dp[1] = f2bf(a * sn + b2 * cs);
  }
}

// ---------------------------------------------------------------------------
// Flash-style attention, LDS-staged (unchanged from round 1/2).
// ---------------------------------------------------------------------------
__global__ __launch_bounds__(256, 1) void attn_kernel(
    const unsigned short* __restrict__ q,
    const void* __restrict__ past_k,
    const unsigned short* __restrict__ k_rot,
    const void* __restrict__ past_v,
    const void* __restrict__ dout,
    unsigned short* __restrict__ attn_out,
    const unsigned short* __restrict__ det)
{
  __shared__ __align__(16) unsigned short K_smem[512 * 64];
  __shared__ __align__(16) unsigned short Vt_smem[64 * 512];
  __shared__ __align__(16) unsigned short p_lds[4][16 * 32];

  const int f32 = detect_f32(det);
  const int bh = blockIdx.x;
  const int b  = bh >> 5;
  const int h  = bh & 31;
  const int tid  = threadIdx.x;
  const int wave = tid >> 6;
  const int lane = tid & 63;
  const int quad = lane >> 4;
  const int l16  = lane & 15;
  const float NEG = -1e30f;

  const unsigned short* qb_ptr = q + (size_t)bh * 256 * 64;
  const unsigned short* krot   = k_rot + (size_t)bh * 256 * 64;
  const size_t kpastBase = ((size_t)bh * 512 + 256) * 64;
  const size_t vpastBase = ((size_t)bh * 512 + 256) * 64;
  const size_t vcurBase  = 25165824 + (size_t)bh * 512 * 64;

#pragma unroll 4
  for (int it = 0; it < 16; ++it) {
    const int lin = it * 256 + tid;
    const int j  = lin >> 3;
    const int d0 = (lin & 7) << 3;
    bf16x8 kv, vv;
    if (j < 256) {
      kv = load8(past_k, kpastBase + (size_t)j * 64 + d0, f32);
      vv = load8(past_v, vpastBase + (size_t)j * 64 + d0, f32);
    } else {
      kv = *(const bf16x8*)&krot[(size_t)(j - 256) * 64 + d0];
      vv = load8(dout, vcurBase + (size_t)j * 64 + d0, f32);
    }
    *(bf16x8*)((char*)K_smem + (j * 128 + ((d0 * 2) ^ ((j & 7) << 4)))) = kv;
    const unsigned short* vs = (const unsigned short*)&vv;
    const int dh = (d0 >> 3) & 7;
    const int jx = j * 2;
#pragma unroll
    for (int i = 0; i < 8; ++i)
      *(unsigned short*)((char*)Vt_smem +
          ((d0 + i) * 1024 + (jx ^ ((i ^ dh) << 4)))) = vs[i];
  }
  __syncthreads();

  unsigned short* pw = p_lds[wave];
  volatile unsigned short* pwv = pw;

  for (int g = 0; g < 4; ++g) {
    const int s = (g & 1) ? (g * 4 + 3 - wave) : (g * 4 + wave);
    const int qbase = s * 16;
    const bf16x8 aq0 = *(const bf16x8*)&qb_ptr[(qbase + l16) * 64 + quad * 8];
    const bf16x8 aq1 = *(const bf16x8*)&qb_ptr[(qbase + l16) * 64 + 32 + quad * 8];
    f32x4 o[4];
#pragma unroll
    for (int nt = 0; nt < 4; ++nt) o[nt] = f32x4{0.f, 0.f, 0.f, 0.f};
    float m_i[4], l_i[4];
#pragma unroll
    for (int r = 0; r < 4; ++r) { m_i[r] = NEG; l_i[r] = 0.f; }

    const int np = ((qbase + 271) >> 5) + 1;

    for (int p = 0; p < np; ++p) {
      const int j0 = p * 32;
      f32x4 s0 = f32x4{0.f, 0.f, 0.f, 0.f};
      f32x4 s1 = f32x4{0.f, 0.f, 0.f, 0.f};
#pragma unroll
      for (int half = 0; half < 2; ++half) {
        const int j = j0 + half * 16 + l16;
        const int krow = j * 128;
        const int ksw  = (j & 7) << 4;
        const bf16x8 kb0 = *(const bf16x8*)((const char*)K_smem +
                           (krow + ((quad * 16) ^ ksw)));
        const bf16x8 kb1 = *(const bf16x8*)((const char*)K_smem +
                           (krow + ((64 + quad * 16) ^ ksw)));
        f32x4& sx = half ? s1 : s0;
        sx = __builtin_amdgcn_mfma_f32_16x16x32_bf16(aq0, kb0, sx, 0, 0, 0);
        sx = __builtin_amdgcn_mfma_f32_16x16x32_bf16(aq1, kb1, sx, 0, 0, 0);
      }
#pragma unroll
      for (int r = 0; r < 4; ++r) {
        const int qrow = qbase + quad * 4 + r;
        float v0 = s0[r] * 0.125f;
        float v1 = s1[r] * 0.125f;
        if (j0 + l16 > qrow + 256)      v0 = NEG;
        if (j0 + 16 + l16 > qrow + 256) v1 = NEG;
        float t = fmaxf(v0, v1);
        t = fmaxf(t, __shfl_xor(t, 1));
        t = fmaxf(t, __shfl_xor(t, 2));
        t = fmaxf(t, __shfl_xor(t, 4));
        t = fmaxf(t, __shfl_xor(t, 8));
        const float mnew = fmaxf(m_i[r], t);
        const float alpha = __expf(m_i[r] - mnew);
        m_i[r] = mnew;
        const float p0 = __expf(v0 - mnew);
        const float p1 = __expf(v1 - mnew);
        float rs = p0 + p1;
        rs += __shfl_xor(rs, 1);
        rs += __shfl_xor(rs, 2);
        rs += __shfl_xor(rs, 4);
        rs += __shfl_xor(rs, 8);
        l_i[r] = l_i[r] * alpha + rs;
        pwv[(quad * 4 + r) * 32 + l16]      = f2bf(p0);
        pwv[(quad * 4 + r) * 32 + 16 + l16] = f2bf(p1);
#pragma unroll
        for (int nt = 0; nt < 4; ++nt) o[nt][r] *= alpha;
      }
      asm volatile("s_waitcnt lgkmcnt(0)" ::: "memory");
      __builtin_amdgcn_sched_barrier(0);
      const bf16x8 ap = *(const bf16x8*)&pw[l16 * 32 + quad * 8];
#pragma unroll
      for (int nt = 0; nt < 4; ++nt) {
        const int d = nt * 16 + l16;
        const int vsw = ((d & 7) ^ ((d >> 3) & 7)) << 4;
        const bf16x8 bv = *(const bf16x8*)((const char*)Vt_smem +
                          (d * 1024 + (((j0 + quad * 8) * 2) ^ vsw)));
        o[nt] = __builtin_amdgcn_mfma_f32_16x16x32_bf16(ap, bv, o[nt], 0, 0, 0);
      }
    }
#pragma unroll
    for (int r = 0; r < 4; ++r) {
      const float inv = 1.0f / l_i[r];
      const int t = qbase + quad * 4 + r;
#pragma unroll
      for (int nt = 0; nt < 4; ++nt) {
        attn_out[((size_t)(b * 256 + t)) * 2048 + h * 64 + nt * 16 + l16] =
            f2bf(o[nt][r] * inv);
      }
    }
  }
}

// ---------------------------------------------------------------------------
extern "C" void kernel_launch(void* const* d_in, const int* in_sizes, int n_in,
                              void* d_out, int out_size, void* d_ws, size_t ws_size,
                              hipStream_t stream)
{
  const void* x      = d_in[0];
  const void* past_k = d_in[1];
  const void* past_v = d_in[2];
  const void* Wq     = d_in[3];
  const void* Wk     = d_in[4];
  const void* Wv     = d_in[5];
  const void* Wo     = d_in[6];
  const int* pos_p   = (const int*)d_in[7];
  const unsigned short* det = (const unsigned short*)x;

  unsigned short* ws = (unsigned short*)d_ws;
  const dim3 gb(256);

  if (ws_size >= (size_t)67108864) {
    // ---- 64 MiB aliased layout (elements) ----
    // [0,        8388608)  q_ws
    // [8388608, 16777216)  xb (dead after QKV gemm)  ∪  ao_ws (born at attn)
    // [16777216,29360128)  wqkv (dead after QKV gemm); krot_ws aliases head
    // [29360128,33554432)  wob
    unsigned short* q_ws    = ws;
    unsigned short* xb      = ws + 8388608;
    unsigned short* ao_ws   = ws + 8388608;
    unsigned short* wqkv    = ws + 16777216;
    unsigned short* krot_ws = ws + 16777216;
    unsigned short* wob     = ws + 29360128;

    // convert (+fused past-slab copy): 4096 convert blocks + 512 copy blocks
    hipLaunchKernelGGL(convert_kernel, dim3(4608), gb, 0, stream,
                       x, Wq, Wk, Wv, Wo, past_k, past_v, d_out,
                       xb, wqkv, wob, det);
    // fused QKV: M=4096, N=6144 -> 1536 blocks (6/CU)
    hipLaunchKernelGGL(gemm_bf16_kernel, dim3(1536), gb, 0, stream,
                       xb, wqkv, (void*)q_ws, d_out, det, 1);
    hipLaunchKernelGGL(rope_kernel, dim3(32768), gb, 0, stream, pos_p, q_ws, d_out, krot_ws, det);
    hipLaunchKernelGGL(attn_kernel, dim3(512), gb, 0, stream,
                       q_ws, past_k, krot_ws, past_v, d_out, ao_ws, det);
    // output projection: M=4096, N=2048 -> 512 blocks
    hipLaunchKernelGGL(gemm_bf16_kernel, dim3(512), gb, 0, stream,
                       ao_ws, wob, d_out, d_out, det, 0);
  } else {
    // ---- legacy 48 MiB path (round-1 behavior) ----
    unsigned short* q_ws    = ws;
    unsigned short* krot_ws = ws + 8388608;
    unsigned short* ao_ws   = ws + 16777216;
    const dim3 gg(32, 16);
    hipLaunchKernelGGL(gemm_bt_kernel, gg, gb, 0, stream, x, Wq, (void*)q_ws, det,
                       1, 1, 0, (size_t)0,        2048, 2048, 1, 256, 0);
    hipLaunchKernelGGL(gemm_bt_kernel, gg, gb, 0, stream, x, Wk, d_out, det,
                       1, 1, 1, (size_t)8388608,  2048, 2048, 1, 512, 256);
    hipLaunchKernelGGL(gemm_bt_kernel, gg, gb, 0, stream, x, Wv, d_out, det,
                       1, 1, 1, (size_t)25165824, 2048, 2048, 1, 512, 256);
    hipLaunchKernelGGL(copy_kernel, dim3(512), gb, 0, stream, past_k, past_v, d_out, det);
    hipLaunchKernelGGL(rope_kernel, dim3(32768), gb, 0, stream, pos_p, q_ws, d_out, krot_ws, det);
    hipLaunchKernelGGL(attn_kernel, dim3(512), gb, 0, stream,
                       q_ws, past_k, krot_ws, past_v, d_out, ao_ws, det);
    hipLaunchKernelGGL(gemm_bt_kernel, gg, gb, 0, stream, (const void*)ao_ws, Wo, d_out, det,
                       0, 1, 1, (size_t)0,        2048, 2048, 0, 0, 0);
  }
}